// Round 7
// baseline (214.948 us; speedup 1.0000x reference)
//
#include <hip/hip_runtime.h>

// YOLO loss: preds (B,7,7,30) f32, labels (B,7,7,30) f32 -> scalar f32 (sum/B).
// R8: persistent double-buffered pipeline with counted vmcnt (never drain to 0
// in steady state). Evidence: R4/R5/R6/R7 (4 diverse structures) all pin at
// 72-78us = 2.6 TB/s with HBM 17%, VALU 10%, L2 8% of ceiling -> concurrency x
// latency bound, not BW bound. Shared flaw: burst->vmcnt(0)->compute phasing
// keeps avg outstanding ~2.6 KB/CU vs ~9 KB needed (Little's law). R8: 1280
// persistent 1-wave blocks (31.7KB LDS = 2 ping-pong tile buffers -> 5
// blocks/CU), each stages tile t+1 (15 DMA + 1 lb0 asm load = exactly 16 vmem
// ops) then s_waitcnt vmcnt(16): tile t guaranteed complete, t+1's 16KB stays
// in flight under compute. Partials bit-identical to R4: same 64-cell shuffle
// tree, same ((w0+w1)+w2)+w3 grouping per 256 cells, same reduce kernel.

#define BATCH 16384
#define S 7
#define C 30
#define NCELLS (BATCH * S * S)      // 802816
#define NBLK 3136                   // partials: one per 256 consecutive cells
#define NW 1280                     // persistent waves (1-wave blocks)

// per-buffer float layout (wave-private), same as R6/R7:
//   [0,1792)    labels staged linear
//   [1792,1920) labels tail (mixed DMA round, lanes 0-31)
//   [1920,2048) preds tail scratch (mixed DMA round, lanes 32-63)
//   [2048,3840) preds staged linear
//   [3840,3968) preds tail (filled by fixup copy from scratch)
#define BUF_FLOATS 3968             // 15872 B; two buffers = 31744 B/block
#define SP_OFF 2048

#define GLOBAL_LOAD_LDS16(g, l)                                         \
    __builtin_amdgcn_global_load_lds(                                   \
        (const __attribute__((address_space(1))) void*)(g),             \
        (__attribute__((address_space(3))) void*)(l), 16, 0, 0)

#define WAIT_VMCNT16()                                                  \
    do { asm volatile("s_waitcnt vmcnt(16)" ::: "memory");              \
         __builtin_amdgcn_sched_barrier(0); } while (0)
#define WAIT_VMCNT0()                                                   \
    do { asm volatile("s_waitcnt vmcnt(0)" ::: "memory");               \
         __builtin_amdgcn_sched_barrier(0); } while (0)

__device__ __forceinline__ float sq(float v) { return v * v; }

__device__ __forceinline__ float iou_box(float acx, float acy, float aw, float ah,
                                         float bcx, float bcy, float bw, float bh) {
    float ax0 = acx - aw * 0.5f, ax1 = acx + aw * 0.5f;
    float ay0 = acy - ah * 0.5f, ay1 = acy + ah * 0.5f;
    float bx0 = bcx - bw * 0.5f, bx1 = bcx + bw * 0.5f;
    float by0 = bcy - bh * 0.5f, by1 = bcy + bh * 0.5f;
    float iw = fmaxf(fminf(ax1, bx1) - fmaxf(ax0, bx0), 0.0f);
    float ih = fmaxf(fminf(ay1, by1) - fmaxf(ay0, by0), 0.0f);
    float inter = iw * ih;
    float denom = aw * ah + bw * bh - inter + 1e-10f;
    return inter / denom;
}

// issue 15 DMA ops staging 64 cells of preds+labels into buffer bf
__device__ __forceinline__ void stage_tile(const float* __restrict__ preds,
                                           const float* __restrict__ labels,
                                           int base_cell, float* bf, int lane) {
    const float4* gp = reinterpret_cast<const float4*>(preds  + (size_t)base_cell * C);
    const float4* gl = reinterpret_cast<const float4*>(labels + (size_t)base_cell * C);
    #pragma unroll
    for (int k = 0; k < 7; ++k)   // labels floats [0,1792)
        GLOBAL_LOAD_LDS16(gl + k * 64 + lane, (char*)bf + (size_t)k * 1024);
    #pragma unroll
    for (int k = 0; k < 7; ++k)   // preds floats [0,1792) -> bf[2048..3840)
        GLOBAL_LOAD_LDS16(gp + k * 64 + lane,
                          (char*)bf + (size_t)SP_OFF * 4 + (size_t)k * 1024);
    // mixed tail: lanes 0-31 labels f4 448+l -> bf floats [1792,1920)
    //             lanes 32-63 preds  f4 448+(l-32) -> bf floats [1920,2048)
    const float4* src = (lane < 32) ? (gl + 448 + lane) : (gp + 448 + (lane - 32));
    GLOBAL_LOAD_LDS16(src, (char*)bf + 7168);
}

// issue the lb0 partner gather (16th vmem op of a tile) via asm so the
// compiler inserts no conservative vmcnt(0) before its use; our manual
// vmcnt(16) guarantees it has landed.
__device__ __forceinline__ float issue_lb0(const float* __restrict__ labels,
                                           int base_cell, int lane) {
    const int cell = base_cell + lane;
    const int b    = cell / (S * S);
    const int rem  = cell - b * (S * S);
    const int y    = rem / S;
    const int x    = rem - y * S;
    const int pc   = b * (S * S) + x * S + y;
    const float* a = labels + (size_t)pc * C;
    float lb;
    asm volatile("global_load_dword %0, %1, off" : "=&v"(lb) : "v"(a) : "memory");
    return lb;
}

// fixup + per-cell loss + 64-lane shuffle tree (identical math to R4/R7).
// Returns the tile sum (valid on lane 0).
__device__ __forceinline__ float compute_tile(float* bf, float lb0, int lane) {
    // fixup: preds tail from scratch bf[1920,2048) -> linear bf[3840,3968)
    {
        float2 v = *reinterpret_cast<const float2*>(&bf[1920 + 2 * lane]);
        *reinterpret_cast<float2*>(&bf[SP_OFF + 1792 + 2 * lane]) = v;
    }
    const float* p = &bf[SP_OFF + lane * C];
    const float* l = &bf[lane * C];
    float pv[C], lv[C];
    #pragma unroll
    for (int i = 0; i < C / 2; ++i) {
        float2 tp = *reinterpret_cast<const float2*>(p + 2 * i);
        pv[2 * i] = tp.x; pv[2 * i + 1] = tp.y;
        float2 tl = *reinterpret_cast<const float2*>(l + 2 * i);
        lv[2 * i] = tl.x; lv[2 * i + 1] = tl.y;
    }

    float iou1 = iou_box(pv[0], pv[1], pv[2], pv[3], lb0, lv[1], lv[2], lv[3]);
    float iou2 = iou_box(pv[5], pv[6], pv[7], pv[8], lb0, lv[1], lv[2], lv[3]);

    float b1 = 5.0f * (sq(pv[0] - lv[0]) + sq(pv[1] - lv[1]))
             + sq(sqrtf(pv[2]) - sqrtf(lv[2])) + sq(sqrtf(pv[3]) - sqrtf(lv[3]))
             + sq(iou1 - pv[4])
             + 0.5f * pv[9] * pv[9];

    float b2 = 5.0f * (sq(pv[5] - lv[5]) + sq(pv[6] - lv[6]))
             + sq(sqrtf(pv[7]) - sqrtf(lv[7])) + sq(sqrtf(pv[8]) - sqrtf(lv[8]))
             + sq(iou2 - pv[9])
             + 0.5f * pv[4] * pv[4];

    float cls = 0.0f;
    #pragma unroll
    for (int c = 10; c < C; ++c) cls += sq(lv[c] - pv[c]);

    float obj_loss   = ((iou1 > iou2) ? b1 : b2) + cls;
    float noobj_loss = 0.5f * (pv[4] * pv[4] + pv[9] * pv[9]);
    float loss = (lv[4] == 1.0f) ? obj_loss : noobj_loss;

    #pragma unroll
    for (int off = 32; off > 0; off >>= 1)
        loss += __shfl_down(loss, off, 64);
    return loss;
}

__global__ __launch_bounds__(64) void yolo_partial_kernel(
        const float* __restrict__ preds,
        const float* __restrict__ labels,
        float* __restrict__ partials) {
    __shared__ __align__(16) float lds[2 * BUF_FLOATS];   // 31744 B -> 5 blk/CU

    const int lane = threadIdx.x;     // 64-thread block = 1 wave
    const int gid  = blockIdx.x;      // 0..NW-1
    // waves 0..575 own 3 groups of 256 cells, 576..1279 own 2 (576*3+704*2=3136)
    const int ngrp  = (gid < 576) ? 3 : 2;
    const int total = 4 * ngrp;       // tiles in this wave's sequence (8 or 12)

    float* bufA = lds;
    float* bufB = lds + BUF_FLOATS;

    // tile seq -> base cell: group = gid + (seq/4)*NW, tile j = seq%4
    #define TILE_BASE(seq) ((gid + ((seq) >> 2) * NW) * 256 + ((seq) & 3) * 64)

    // prologue: fill pipeline with tile 0
    stage_tile(preds, labels, TILE_BASE(0), bufA, lane);
    float lbA = issue_lb0(labels, TILE_BASE(0), lane);
    float lbB = 0.0f;

    float gsum = 0.0f;
    int grp_out = gid;

    for (int s = 0; s < total; s += 2) {
        // ---- even step: stage s+1 into B (always valid: total is even), compute A
        stage_tile(preds, labels, TILE_BASE(s + 1), bufB, lane);
        lbB = issue_lb0(labels, TILE_BASE(s + 1), lane);
        WAIT_VMCNT16();               // tile s complete; s+1 stays in flight
        {
            float w = compute_tile(bufA, lbA, lane);
            gsum = ((s & 3) == 0) ? w : gsum + w;   // ((w0+w1)+w2)+w3 order
        }
        // ---- odd step: stage s+2 into A if present, compute B
        if (s + 2 < total) {
            stage_tile(preds, labels, TILE_BASE(s + 2), bufA, lane);
            lbA = issue_lb0(labels, TILE_BASE(s + 2), lane);
            WAIT_VMCNT16();
        } else {
            WAIT_VMCNT0();            // epilogue drain
        }
        {
            float w = compute_tile(bufB, lbB, lane);
            gsum = gsum + w;          // seq s+1 is odd, never group-start
            if (((s + 1) & 3) == 3) { // group of 4 tiles done -> one partial
                if (lane == 0) partials[grp_out] = gsum;
                grp_out += NW;
            }
        }
    }
    #undef TILE_BASE
}

__global__ __launch_bounds__(256) void yolo_reduce_kernel(
        const float* __restrict__ partials,
        float* __restrict__ out) {
    const int tid = threadIdx.x;
    float s = 0.0f;
    for (int i = tid; i < NBLK; i += 256) s += partials[i];

    #pragma unroll
    for (int off = 32; off > 0; off >>= 1)
        s += __shfl_down(s, off, 64);

    __shared__ float wsum[4];
    int lane = tid & 63;
    int wv   = tid >> 6;
    if (lane == 0) wsum[wv] = s;
    __syncthreads();
    if (tid == 0) {
        out[0] = (wsum[0] + wsum[1] + wsum[2] + wsum[3]) * (1.0f / (float)BATCH);
    }
}

extern "C" void kernel_launch(void* const* d_in, const int* in_sizes, int n_in,
                              void* d_out, int out_size, void* d_ws, size_t ws_size,
                              hipStream_t stream) {
    const float* preds  = (const float*)d_in[0];
    const float* labels = (const float*)d_in[1];
    float* out = (float*)d_out;
    float* partials = (float*)d_ws;   // NBLK floats = 12.25 KB (unchanged)

    yolo_partial_kernel<<<NW, 64, 0, stream>>>(preds, labels, partials);
    yolo_reduce_kernel<<<1, 256, 0, stream>>>(partials, out);
}

// Round 8
// 205.070 us; speedup vs baseline: 1.0482x; 1.0482x over previous
//
#include <hip/hip_runtime.h>

// YOLO loss: preds (B,7,7,30) f32, labels (B,7,7,30) f32 -> scalar f32 (sum/B).
// R9: final discriminator — replace the global_load_lds DMA staging (used by
// every fast variant R4/R6/R7/R8, all pinned at 72-78us = 2.6 TB/s) with
// plain coalesced reg-staging: 30x global_load_dwordx2 per thread (wave reads
// 1KB contiguous per instr, 8 lines/instr — transaction-cheap, unlike R5's
// stride-120B loads) -> ds_write_b64 -> barrier -> identical compute.
// ~15KB in flight per wave, ~120KB/CU: max-MLP, no DMA path. If this is ALSO
// flat, the 2.6 TB/s ceiling spans {DMA, strided-direct, reg-staged-coalesced}
// x {convoy, wave-drain, counted-vmcnt, persistent} -> hardware ceiling,
// declare roofline. Structure/partials bit-identical to R4 (same grid, same
// shuffle tree, same wsum order) -> absmax 0.0.

#define BATCH 16384
#define S 7
#define C 30
#define NCELLS (BATCH * S * S)    // 802816
#define BLOCK 256
#define NC 256                    // cells per block
#define NBLK (NCELLS / NC)        // 3136
#define F2_PER_ARR (NC * C / 2)   // 3840 float2 per array per block
#define PER_THR (F2_PER_ARR / BLOCK)   // 15

__device__ __forceinline__ float sq(float v) { return v * v; }

__device__ __forceinline__ float iou_box(float acx, float acy, float aw, float ah,
                                         float bcx, float bcy, float bw, float bh) {
    float ax0 = acx - aw * 0.5f, ax1 = acx + aw * 0.5f;
    float ay0 = acy - ah * 0.5f, ay1 = acy + ah * 0.5f;
    float bx0 = bcx - bw * 0.5f, bx1 = bcx + bw * 0.5f;
    float by0 = bcy - bh * 0.5f, by1 = bcy + bh * 0.5f;
    float iw = fmaxf(fminf(ax1, bx1) - fmaxf(ax0, bx0), 0.0f);
    float ih = fmaxf(fminf(ay1, by1) - fmaxf(ay0, by0), 0.0f);
    float inter = iw * ih;
    float denom = aw * ah + bw * bh - inter + 1e-10f;
    return inter / denom;
}

__global__ __launch_bounds__(BLOCK) void yolo_partial_kernel(
        const float* __restrict__ preds,
        const float* __restrict__ labels,
        float* __restrict__ partials) {
    __shared__ __align__(16) float sp[NC * C];   // 30720 B
    __shared__ __align__(16) float sl[NC * C];   // 30720 B

    const int tid  = threadIdx.x;
    const int lane = tid & 63;
    const int wv   = tid >> 6;
    const int base_cell = blockIdx.x * NC;

    const float2* gp = reinterpret_cast<const float2*>(preds  + (size_t)base_cell * C);
    const float2* gl = reinterpret_cast<const float2*>(labels + (size_t)base_cell * C);

    // ---- reg-staging: issue all 30 coalesced float2 loads back-to-back ----
    float2 rl[PER_THR], rp[PER_THR];
    #pragma unroll
    for (int k = 0; k < PER_THR; ++k) rl[k] = gl[tid + k * BLOCK];
    #pragma unroll
    for (int k = 0; k < PER_THR; ++k) rp[k] = gp[tid + k * BLOCK];

    // ---- land in LDS (2-way bank aliasing on b64: free per m136) ----
    #pragma unroll
    for (int k = 0; k < PER_THR; ++k)
        reinterpret_cast<float2*>(sl)[tid + k * BLOCK] = rl[k];
    #pragma unroll
    for (int k = 0; k < PER_THR; ++k)
        reinterpret_cast<float2*>(sp)[tid + k * BLOCK] = rp[k];
    __syncthreads();

    // ---- per-cell compute from LDS (identical to R4) ----
    const float* p = sp + tid * C;
    const float* l = sl + tid * C;
    float pv[C], lv[C];
    #pragma unroll
    for (int i = 0; i < C / 2; ++i) {
        float2 tp = *reinterpret_cast<const float2*>(p + 2 * i);
        pv[2 * i] = tp.x; pv[2 * i + 1] = tp.y;
        float2 tl = *reinterpret_cast<const float2*>(l + 2 * i);
        lv[2 * i] = tl.x; lv[2 * i + 1] = tl.y;
    }

    // transposed label x-coord quirk: labels[b, x, y, 0]
    int cell = base_cell + tid;
    int b    = cell / (S * S);
    int rem  = cell - b * (S * S);
    int y    = rem / S;
    int x    = rem - y * S;
    int pc   = b * (S * S) + x * S + y;       // partner cell index
    float lb0;
    if (pc >= base_cell && pc < base_cell + NC) {
        lb0 = sl[(pc - base_cell) * C];
    } else {
        lb0 = labels[(size_t)pc * C];         // rare: image straddles block edge
    }

    float iou1 = iou_box(pv[0], pv[1], pv[2], pv[3], lb0, lv[1], lv[2], lv[3]);
    float iou2 = iou_box(pv[5], pv[6], pv[7], pv[8], lb0, lv[1], lv[2], lv[3]);

    float b1 = 5.0f * (sq(pv[0] - lv[0]) + sq(pv[1] - lv[1]))
             + sq(sqrtf(pv[2]) - sqrtf(lv[2])) + sq(sqrtf(pv[3]) - sqrtf(lv[3]))
             + sq(iou1 - pv[4])
             + 0.5f * pv[9] * pv[9];

    float b2 = 5.0f * (sq(pv[5] - lv[5]) + sq(pv[6] - lv[6]))
             + sq(sqrtf(pv[7]) - sqrtf(lv[7])) + sq(sqrtf(pv[8]) - sqrtf(lv[8]))
             + sq(iou2 - pv[9])
             + 0.5f * pv[4] * pv[4];

    float cls = 0.0f;
    #pragma unroll
    for (int c = 10; c < C; ++c) cls += sq(lv[c] - pv[c]);

    float obj_loss   = ((iou1 > iou2) ? b1 : b2) + cls;
    float noobj_loss = 0.5f * (pv[4] * pv[4] + pv[9] * pv[9]);
    float loss = (lv[4] == 1.0f) ? obj_loss : noobj_loss;

    // ---- reduction: identical tree/order to R4 -> bit-identical partials ----
    #pragma unroll
    for (int off = 32; off > 0; off >>= 1)
        loss += __shfl_down(loss, off, 64);

    __shared__ float wsum[BLOCK / 64];
    if (lane == 0) wsum[wv] = loss;
    __syncthreads();
    if (tid == 0) {
        partials[blockIdx.x] = wsum[0] + wsum[1] + wsum[2] + wsum[3];
    }
}

__global__ __launch_bounds__(BLOCK) void yolo_reduce_kernel(
        const float* __restrict__ partials,
        float* __restrict__ out) {
    const int tid = threadIdx.x;
    float s = 0.0f;
    for (int i = tid; i < NBLK; i += BLOCK) s += partials[i];

    #pragma unroll
    for (int off = 32; off > 0; off >>= 1)
        s += __shfl_down(s, off, 64);

    __shared__ float wsum[BLOCK / 64];
    int lane = tid & 63;
    int wv   = tid >> 6;
    if (lane == 0) wsum[wv] = s;
    __syncthreads();
    if (tid == 0) {
        out[0] = (wsum[0] + wsum[1] + wsum[2] + wsum[3]) * (1.0f / (float)BATCH);
    }
}

extern "C" void kernel_launch(void* const* d_in, const int* in_sizes, int n_in,
                              void* d_out, int out_size, void* d_ws, size_t ws_size,
                              hipStream_t stream) {
    const float* preds  = (const float*)d_in[0];
    const float* labels = (const float*)d_in[1];
    float* out = (float*)d_out;
    float* partials = (float*)d_ws;   // NBLK floats = 12.25 KB

    yolo_partial_kernel<<<NBLK, BLOCK, 0, stream>>>(preds, labels, partials);
    yolo_reduce_kernel<<<1, BLOCK, 0, stream>>>(partials, out);
}

// Round 9
// 197.027 us; speedup vs baseline: 1.0910x; 1.0408x over previous
//
#include <hip/hip_runtime.h>

// YOLO loss: preds (B,7,7,30) f32, labels (B,7,7,30) f32 -> scalar f32 (sum/B).
// R10: last untested subsystem knob — cache allocation policy. Six structures
// x three load paths (DMA / strided-direct / reg-staged-coalesced) all pin at
// 72-78us = 2.6 TB/s delivered with every pipe <20% busy; per-CU cycle models
// predict 6-15us. Shared path: L2-miss service. Counter clue: FETCH_SIZE
// stays ~97MB/iter though the 193MB set fits the 256MB L3 -> stream gets only
// ~50% L3 residency (streaming/limited-allocate policy suspected). R10 = R9
// structure with __builtin_nontemporal_load (nt bit) on the bulk float4
// streams (16B/lane, m13 shape); lb0 gather stays cached. Compute/reduction
// bit-identical to R4/R9 -> absmax 0.0. Outcomes pre-committed: faster ->
// policy was the wall; slower -> L3 hits load-bearing (revert); flat ->
// declare roofline (environmental wall established).

#define BATCH 16384
#define S 7
#define C 30
#define NCELLS (BATCH * S * S)    // 802816
#define BLOCK 256
#define NC 256                    // cells per block
#define NBLK (NCELLS / NC)        // 3136
#define F4_PER_ARR (NC * C / 4)   // 1920 float4 per array per block

typedef float f4v __attribute__((ext_vector_type(4)));

__device__ __forceinline__ f4v ntld(const f4v* p) {
    return __builtin_nontemporal_load(p);
}

__device__ __forceinline__ float sq(float v) { return v * v; }

__device__ __forceinline__ float iou_box(float acx, float acy, float aw, float ah,
                                         float bcx, float bcy, float bw, float bh) {
    float ax0 = acx - aw * 0.5f, ax1 = acx + aw * 0.5f;
    float ay0 = acy - ah * 0.5f, ay1 = acy + ah * 0.5f;
    float bx0 = bcx - bw * 0.5f, bx1 = bcx + bw * 0.5f;
    float by0 = bcy - bh * 0.5f, by1 = bcy + bh * 0.5f;
    float iw = fmaxf(fminf(ax1, bx1) - fmaxf(ax0, bx0), 0.0f);
    float ih = fmaxf(fminf(ay1, by1) - fmaxf(ay0, by0), 0.0f);
    float inter = iw * ih;
    float denom = aw * ah + bw * bh - inter + 1e-10f;
    return inter / denom;
}

__global__ __launch_bounds__(BLOCK) void yolo_partial_kernel(
        const float* __restrict__ preds,
        const float* __restrict__ labels,
        float* __restrict__ partials) {
    __shared__ __align__(16) float sp[NC * C];   // 30720 B
    __shared__ __align__(16) float sl[NC * C];   // 30720 B

    const int tid  = threadIdx.x;
    const int lane = tid & 63;
    const int wv   = tid >> 6;
    const int base_cell = blockIdx.x * NC;

    const f4v* gp = reinterpret_cast<const f4v*>(preds  + (size_t)base_cell * C);
    const f4v* gl = reinterpret_cast<const f4v*>(labels + (size_t)base_cell * C);
    f4v* s4l = reinterpret_cast<f4v*>(sl);
    f4v* s4p = reinterpret_cast<f4v*>(sp);

    // ---- nontemporal float4 reg-staging: 7 rounds + 128-f4 tail per array ----
    f4v rl[8], rp[8];
    #pragma unroll
    for (int k = 0; k < 7; ++k) rl[k] = ntld(gl + tid + k * BLOCK);
    #pragma unroll
    for (int k = 0; k < 7; ++k) rp[k] = ntld(gp + tid + k * BLOCK);
    // tail: waves 0-1 labels f4 [1792,1920), waves 2-3 preds f4 [1792,1920)
    const int tl = 1792 + (tid & 127);
    if (tid < 128) rl[7] = ntld(gl + tl);
    else           rp[7] = ntld(gp + tl);

    #pragma unroll
    for (int k = 0; k < 7; ++k) s4l[tid + k * BLOCK] = rl[k];
    #pragma unroll
    for (int k = 0; k < 7; ++k) s4p[tid + k * BLOCK] = rp[k];
    if (tid < 128) s4l[tl] = rl[7];
    else           s4p[tl] = rp[7];
    __syncthreads();

    // ---- per-cell compute from LDS (identical to R4/R9) ----
    const float* p = sp + tid * C;
    const float* l = sl + tid * C;
    float pv[C], lv[C];
    #pragma unroll
    for (int i = 0; i < C / 2; ++i) {
        float2 tp = *reinterpret_cast<const float2*>(p + 2 * i);
        pv[2 * i] = tp.x; pv[2 * i + 1] = tp.y;
        float2 tl2 = *reinterpret_cast<const float2*>(l + 2 * i);
        lv[2 * i] = tl2.x; lv[2 * i + 1] = tl2.y;
    }

    // transposed label x-coord quirk: labels[b, x, y, 0]
    int cell = base_cell + tid;
    int b    = cell / (S * S);
    int rem  = cell - b * (S * S);
    int y    = rem / S;
    int x    = rem - y * S;
    int pc   = b * (S * S) + x * S + y;       // partner cell index
    float lb0;
    if (pc >= base_cell && pc < base_cell + NC) {
        lb0 = sl[(pc - base_cell) * C];
    } else {
        lb0 = labels[(size_t)pc * C];         // rare: image straddles block edge
    }

    float iou1 = iou_box(pv[0], pv[1], pv[2], pv[3], lb0, lv[1], lv[2], lv[3]);
    float iou2 = iou_box(pv[5], pv[6], pv[7], pv[8], lb0, lv[1], lv[2], lv[3]);

    float b1 = 5.0f * (sq(pv[0] - lv[0]) + sq(pv[1] - lv[1]))
             + sq(sqrtf(pv[2]) - sqrtf(lv[2])) + sq(sqrtf(pv[3]) - sqrtf(lv[3]))
             + sq(iou1 - pv[4])
             + 0.5f * pv[9] * pv[9];

    float b2 = 5.0f * (sq(pv[5] - lv[5]) + sq(pv[6] - lv[6]))
             + sq(sqrtf(pv[7]) - sqrtf(lv[7])) + sq(sqrtf(pv[8]) - sqrtf(lv[8]))
             + sq(iou2 - pv[9])
             + 0.5f * pv[4] * pv[4];

    float cls = 0.0f;
    #pragma unroll
    for (int c = 10; c < C; ++c) cls += sq(lv[c] - pv[c]);

    float obj_loss   = ((iou1 > iou2) ? b1 : b2) + cls;
    float noobj_loss = 0.5f * (pv[4] * pv[4] + pv[9] * pv[9]);
    float loss = (lv[4] == 1.0f) ? obj_loss : noobj_loss;

    // ---- reduction: identical tree/order to R4 -> bit-identical partials ----
    #pragma unroll
    for (int off = 32; off > 0; off >>= 1)
        loss += __shfl_down(loss, off, 64);

    __shared__ float wsum[BLOCK / 64];
    if (lane == 0) wsum[wv] = loss;
    __syncthreads();
    if (tid == 0) {
        partials[blockIdx.x] = wsum[0] + wsum[1] + wsum[2] + wsum[3];
    }
}

__global__ __launch_bounds__(BLOCK) void yolo_reduce_kernel(
        const float* __restrict__ partials,
        float* __restrict__ out) {
    const int tid = threadIdx.x;
    float s = 0.0f;
    for (int i = tid; i < NBLK; i += BLOCK) s += partials[i];

    #pragma unroll
    for (int off = 32; off > 0; off >>= 1)
        s += __shfl_down(s, off, 64);

    __shared__ float wsum[BLOCK / 64];
    int lane = tid & 63;
    int wv   = tid >> 6;
    if (lane == 0) wsum[wv] = s;
    __syncthreads();
    if (tid == 0) {
        out[0] = (wsum[0] + wsum[1] + wsum[2] + wsum[3]) * (1.0f / (float)BATCH);
    }
}

extern "C" void kernel_launch(void* const* d_in, const int* in_sizes, int n_in,
                              void* d_out, int out_size, void* d_ws, size_t ws_size,
                              hipStream_t stream) {
    const float* preds  = (const float*)d_in[0];
    const float* labels = (const float*)d_in[1];
    float* out = (float*)d_out;
    float* partials = (float*)d_ws;   // NBLK floats = 12.25 KB

    yolo_partial_kernel<<<NBLK, BLOCK, 0, stream>>>(preds, labels, partials);
    yolo_reduce_kernel<<<1, BLOCK, 0, stream>>>(partials, out);
}